// Round 1
// baseline (438.052 us; speedup 1.0000x reference)
//
#include <hip/hip_runtime.h>
#include <hip/hip_bf16.h>

#define GN 50000
#define GE 800000
#define GD 96
#define GC 40
#define L2EPS 1e-12f

// rp[i] = first edge index e with row[e] >= i  (row sorted); rp[GN] = GE
__global__ void build_rp_k(const int* __restrict__ row, int* __restrict__ rp) {
    int i = blockIdx.x * blockDim.x + threadIdx.x;
    if (i > GN) return;
    int lo = 0, hi = GE;
    while (lo < hi) {
        int mid = (lo + hi) >> 1;
        if (row[mid] < i) lo = mid + 1; else hi = mid;
    }
    rp[i] = lo;
}

// O[N,96] = A[N,96] @ W[96,96], W staged in LDS (36 KB)
__global__ void gemm96_k(const float* __restrict__ A, const float* __restrict__ W,
                         float* __restrict__ O) {
    __shared__ float w[GD * GD];
    for (int i = threadIdx.x; i < GD * GD; i += blockDim.x) w[i] = W[i];
    __syncthreads();
    const int total = GN * GD;
    for (int idx = blockIdx.x * blockDim.x + threadIdx.x; idx < total;
         idx += gridDim.x * blockDim.x) {
        int r = idx / GD;
        int c = idx - r * GD;
        const float* a = A + (size_t)r * GD;
        float acc = 0.f;
#pragma unroll
        for (int k = 0; k < GD; ++k) acc += a[k] * w[k * GD + c];
        O[idx] = acc;
    }
}

// H[n,d] = relu( sum_{e in [rp[n],rp[n+1])} vals[e] * T[col[e], d] )
__global__ void spmm_relu_k(const int* __restrict__ rp, const int* __restrict__ col,
                            const float* __restrict__ vals, const float* __restrict__ T,
                            float* __restrict__ H) {
    int idx = blockIdx.x * blockDim.x + threadIdx.x;
    if (idx >= GN * GD) return;
    int n = idx / GD;
    int d = idx - n * GD;
    int e0 = rp[n], e1 = rp[n + 1];
    float acc = 0.f;
    for (int e = e0; e < e1; ++e) {
        acc += vals[e] * T[(size_t)col[e] * GD + d];
    }
    H[idx] = fmaxf(acc, 0.f);
}

// per-node: l2-normalize row (in place on OUT), then probs = softmax(out @ wc + bc)
__global__ void norm_cls_k(float* __restrict__ OUT, const float* __restrict__ WC,
                           const float* __restrict__ BC, float* __restrict__ PROBS) {
    const int node = blockIdx.x;
    const int t = threadIdx.x;            // block of 128, threads 0..95 carry D
    __shared__ float sq[128];
    __shared__ float srow[GD];
    __shared__ float slog[GC];

    float v = 0.f;
    if (t < GD) v = OUT[(size_t)node * GD + t];
    sq[t] = v * v;
    __syncthreads();
#pragma unroll
    for (int s = 64; s > 0; s >>= 1) {
        if (t < s) sq[t] += sq[t + s];
        __syncthreads();
    }
    float scale = 1.0f / sqrtf(fmaxf(sq[0], L2EPS));
    float o = v * scale;
    if (t < GD) {
        OUT[(size_t)node * GD + t] = o;
        srow[t] = o;
    }
    __syncthreads();

    if (t < GC) {
        float acc = BC[t];
#pragma unroll
        for (int k = 0; k < GD; ++k) acc += srow[k] * WC[k * GC + t];
        slog[t] = acc;
    }
    __syncthreads();

    if (t < GC) {
        float m = -1e30f;
#pragma unroll
        for (int k = 0; k < GC; ++k) m = fmaxf(m, slog[k]);
        float s = 0.f;
#pragma unroll
        for (int k = 0; k < GC; ++k) s += expf(slog[k] - m);
        PROBS[(size_t)node * GC + t] = expf(slog[t] - m) / s;
    }
}

extern "C" void kernel_launch(void* const* d_in, const int* in_sizes, int n_in,
                              void* d_out, int out_size, void* d_ws, size_t ws_size,
                              hipStream_t stream) {
    const int*   row  = (const int*)d_in[0];
    const int*   col  = (const int*)d_in[1];
    const float* vals = (const float*)d_in[2];
    const float* x    = (const float*)d_in[3];
    const float* w1   = (const float*)d_in[4];
    const float* w2   = (const float*)d_in[5];
    const float* wc   = (const float*)d_in[6];
    const float* bc   = (const float*)d_in[7];

    float* out   = (float*)d_out;                 // [N, D]
    float* probs = out + (size_t)GN * GD;         // [N, C]

    char* ws   = (char*)d_ws;
    int*  rp   = (int*)ws;                                      // (N+1) ints
    float* buf = (float*)(ws + ((((size_t)(GN + 1) * 4) + 511) & ~(size_t)511)); // [N, D]

    // 1. CSR row pointers
    build_rp_k<<<(GN + 1 + 255) / 256, 256, 0, stream>>>(row, rp);
    // 2. t1 = x @ w1
    gemm96_k<<<1024, 256, 0, stream>>>(x, w1, buf);
    // 3. h1 = relu(A @ t1)  -> lives in d_out[0:N*D]
    spmm_relu_k<<<(GN * GD + 255) / 256, 256, 0, stream>>>(rp, col, vals, buf, out);
    // 4. t2 = h1 @ w2
    gemm96_k<<<1024, 256, 0, stream>>>(out, w2, buf);
    // 5. h2 = relu(A @ t2)  -> d_out[0:N*D]
    spmm_relu_k<<<(GN * GD + 255) / 256, 256, 0, stream>>>(rp, col, vals, buf, out);
    // 6. normalize in place + classifier softmax
    norm_cls_k<<<GN, 128, 0, stream>>>(out, wc, bc, probs);
}

// Round 2
// 196.183 us; speedup vs baseline: 2.2329x; 2.2329x over previous
//
#include <hip/hip_runtime.h>
#include <hip/hip_bf16.h>

#define GN 50000
#define GE 800000
#define GD 96
#define GC 40
#define L2EPS 1e-12f

// rp[i] = first edge index e with row[e] >= i  (row sorted); rp[GN] = GE
__global__ void build_rp_k(const int* __restrict__ row, int* __restrict__ rp) {
    int i = blockIdx.x * blockDim.x + threadIdx.x;
    if (i > GN) return;
    int lo = 0, hi = GE;
    while (lo < hi) {
        int mid = (lo + hi) >> 1;
        if (row[mid] < i) lo = mid + 1; else hi = mid;
    }
    rp[i] = lo;
}

// pack (col, val) into one 8B record for single-load edge access
__global__ void pack_edges_k(const int* __restrict__ col, const float* __restrict__ vals,
                             int2* __restrict__ ep) {
    int e = blockIdx.x * blockDim.x + threadIdx.x;
    if (e >= GE) return;
    ep[e] = make_int2(col[e], __float_as_int(vals[e]));
}

// O[N,96] = A[N,96] @ W[96,96]; 4 rows x 4 cols per thread, W in LDS as float4[96][24]
__global__ void gemm96_k(const float* __restrict__ A, const float* __restrict__ W,
                         float* __restrict__ O) {
    __shared__ float4 w4[GD * 24];
    const float4* W4 = reinterpret_cast<const float4*>(W);
    for (int i = threadIdx.x; i < GD * 24; i += blockDim.x) w4[i] = W4[i];
    __syncthreads();
    const int total = (GN / 4) * 24;   // 300000 threads: each 4 rows x 1 col-quad
    for (int idx = blockIdx.x * blockDim.x + threadIdx.x; idx < total;
         idx += gridDim.x * blockDim.x) {
        int rq = idx / 24;
        int q  = idx - rq * 24;
        int r0 = rq * 4;
        const float* a = A + (size_t)r0 * GD;
        float4 acc0 = {0,0,0,0}, acc1 = {0,0,0,0}, acc2 = {0,0,0,0}, acc3 = {0,0,0,0};
        for (int k0 = 0; k0 < GD; k0 += 4) {
            float4 a0 = *reinterpret_cast<const float4*>(a + k0);
            float4 a1 = *reinterpret_cast<const float4*>(a + GD + k0);
            float4 a2 = *reinterpret_cast<const float4*>(a + 2 * GD + k0);
            float4 a3 = *reinterpret_cast<const float4*>(a + 3 * GD + k0);
#pragma unroll
            for (int kk = 0; kk < 4; ++kk) {
                float4 w = w4[(k0 + kk) * 24 + q];
                float s0 = ((const float*)&a0)[kk];
                float s1 = ((const float*)&a1)[kk];
                float s2 = ((const float*)&a2)[kk];
                float s3 = ((const float*)&a3)[kk];
                acc0.x += s0 * w.x; acc0.y += s0 * w.y; acc0.z += s0 * w.z; acc0.w += s0 * w.w;
                acc1.x += s1 * w.x; acc1.y += s1 * w.y; acc1.z += s1 * w.z; acc1.w += s1 * w.w;
                acc2.x += s2 * w.x; acc2.y += s2 * w.y; acc2.z += s2 * w.z; acc2.w += s2 * w.w;
                acc3.x += s3 * w.x; acc3.y += s3 * w.y; acc3.z += s3 * w.z; acc3.w += s3 * w.w;
            }
        }
        float4* O4 = reinterpret_cast<float4*>(O);
        O4[(size_t)(r0 + 0) * 24 + q] = acc0;
        O4[(size_t)(r0 + 1) * 24 + q] = acc1;
        O4[(size_t)(r0 + 2) * 24 + q] = acc2;
        O4[(size_t)(r0 + 3) * 24 + q] = acc3;
    }
}

// H[n, q*4..q*4+3] = relu( sum_e vals[e] * T[col[e], q*4..] ), one float4 per thread
__global__ void spmm_relu_k(const int* __restrict__ rp, const int2* __restrict__ ep,
                            const float* __restrict__ T, float* __restrict__ H) {
    int idx = blockIdx.x * blockDim.x + threadIdx.x;
    if (idx >= GN * 24) return;
    int n = idx / 24;
    int q = idx - n * 24;
    int e0 = rp[n], e1 = rp[n + 1];
    const float4* T4 = reinterpret_cast<const float4*>(T);
    float4 acc = {0, 0, 0, 0};
#pragma unroll 4
    for (int e = e0; e < e1; ++e) {
        int2 p = ep[e];
        float4 t = T4[(size_t)p.x * 24 + q];
        float v = __int_as_float(p.y);
        acc.x += v * t.x; acc.y += v * t.y; acc.z += v * t.z; acc.w += v * t.w;
    }
    float4 r;
    r.x = fmaxf(acc.x, 0.f); r.y = fmaxf(acc.y, 0.f);
    r.z = fmaxf(acc.z, 0.f); r.w = fmaxf(acc.w, 0.f);
    reinterpret_cast<float4*>(H)[idx] = r;
}

// wave-per-node: l2-normalize row in place, probs = softmax(out @ wc + bc)
__global__ void norm_cls_k(float* __restrict__ OUT, const float* __restrict__ WC,
                           const float* __restrict__ BC, float* __restrict__ PROBS) {
    __shared__ float wlds[GD * GC];      // 96x40 = 15360 B
    __shared__ float srow[4][GD];
    for (int i = threadIdx.x; i < GD * GC; i += blockDim.x) wlds[i] = WC[i];
    __syncthreads();

    const int w = threadIdx.x >> 6;
    const int l = threadIdx.x & 63;
    const int n = blockIdx.x * 4 + w;    // 12500 blocks x 4 waves, exact
    float* orow = OUT + (size_t)n * GD;

    float oa = orow[l];
    float ob = (l < 32) ? orow[64 + l] : 0.f;
    float ss = oa * oa + ob * ob;
#pragma unroll
    for (int s = 32; s; s >>= 1) ss += __shfl_xor(ss, s);
    float scale = rsqrtf(fmaxf(ss, L2EPS));
    oa *= scale; ob *= scale;
    orow[l] = oa;
    srow[w][l] = oa;
    if (l < 32) { orow[64 + l] = ob; srow[w][64 + l] = ob; }
    // wave-private LDS region: in-wave program order + compiler lgkmcnt suffices

    float logit = -1e30f;
    if (l < GC) {
        float acc = BC[l];
#pragma unroll 8
        for (int k = 0; k < GD; ++k) acc += srow[w][k] * wlds[k * GC + l];
        logit = acc;
    }
    float m = logit;
#pragma unroll
    for (int s = 32; s; s >>= 1) m = fmaxf(m, __shfl_xor(m, s));
    float e = expf(logit - m);           // inactive lanes -> 0
    float sum = e;
#pragma unroll
    for (int s = 32; s; s >>= 1) sum += __shfl_xor(sum, s);
    if (l < GC) PROBS[(size_t)n * GC + l] = e / sum;
}

extern "C" void kernel_launch(void* const* d_in, const int* in_sizes, int n_in,
                              void* d_out, int out_size, void* d_ws, size_t ws_size,
                              hipStream_t stream) {
    const int*   row  = (const int*)d_in[0];
    const int*   col  = (const int*)d_in[1];
    const float* vals = (const float*)d_in[2];
    const float* x    = (const float*)d_in[3];
    const float* w1   = (const float*)d_in[4];
    const float* w2   = (const float*)d_in[5];
    const float* wc   = (const float*)d_in[6];
    const float* bc   = (const float*)d_in[7];

    float* out   = (float*)d_out;                 // [N, D]
    float* probs = out + (size_t)GN * GD;         // [N, C]

    char*  ws  = (char*)d_ws;
    int*   rp  = (int*)ws;                                        // (N+1) ints
    size_t off = (((size_t)(GN + 1) * 4) + 511) & ~(size_t)511;
    float* buf = (float*)(ws + off);                              // [N, D]
    off += (size_t)GN * GD * 4;
    off = (off + 511) & ~(size_t)511;
    int2* ep   = (int2*)(ws + off);                               // [E] packed edges

    build_rp_k<<<(GN + 1 + 255) / 256, 256, 0, stream>>>(row, rp);
    pack_edges_k<<<(GE + 255) / 256, 256, 0, stream>>>(col, vals, ep);
    // t1 = x @ w1
    gemm96_k<<<1172, 256, 0, stream>>>(x, w1, buf);
    // h1 = relu(A @ t1) -> d_out
    spmm_relu_k<<<(GN * 24 + 255) / 256, 256, 0, stream>>>(rp, ep, buf, out);
    // t2 = h1 @ w2
    gemm96_k<<<1172, 256, 0, stream>>>(out, w2, buf);
    // h2 = relu(A @ t2) -> d_out
    spmm_relu_k<<<(GN * 24 + 255) / 256, 256, 0, stream>>>(rp, ep, buf, out);
    // normalize + classifier
    norm_cls_k<<<GN / 4, 256, 0, stream>>>(out, wc, bc, probs);
}

// Round 3
// 190.728 us; speedup vs baseline: 2.2967x; 1.0286x over previous
//
#include <hip/hip_runtime.h>
#include <hip/hip_bf16.h>

#define GN 50000
#define GE 800000
#define GD 96
#define GC 40
#define L2EPS 1e-12f

// merged: rp[i] = lower_bound(row, i) for i<=GN ; ep[e] = (col[e], vals[e])
__global__ void prep_k(const int* __restrict__ row, const int* __restrict__ col,
                       const float* __restrict__ vals, int* __restrict__ rp,
                       int2* __restrict__ ep) {
    int i = blockIdx.x * blockDim.x + threadIdx.x;
    if (i < GE) ep[i] = make_int2(col[i], __float_as_int(vals[i]));
    if (i <= GN) {
        int lo = 0, hi = GE;
        while (lo < hi) {
            int mid = (lo + hi) >> 1;
            if (row[mid] < i) lo = mid + 1; else hi = mid;
        }
        rp[i] = lo;
    }
}

// O[N,96] = A[N,96] @ W[96,96]; 4 rows x 4 cols per thread, W in LDS as float4[96][24]
__global__ void gemm96_k(const float* __restrict__ A, const float* __restrict__ W,
                         float* __restrict__ O) {
    __shared__ float4 w4[GD * 24];
    const float4* W4 = reinterpret_cast<const float4*>(W);
    for (int i = threadIdx.x; i < GD * 24; i += blockDim.x) w4[i] = W4[i];
    __syncthreads();
    const int total = (GN / 4) * 24;   // 300000 threads: each 4 rows x 1 col-quad
    for (int idx = blockIdx.x * blockDim.x + threadIdx.x; idx < total;
         idx += gridDim.x * blockDim.x) {
        int rq = idx / 24;
        int q  = idx - rq * 24;
        int r0 = rq * 4;
        const float* a = A + (size_t)r0 * GD;
        float4 acc0 = {0,0,0,0}, acc1 = {0,0,0,0}, acc2 = {0,0,0,0}, acc3 = {0,0,0,0};
        for (int k0 = 0; k0 < GD; k0 += 4) {
            float4 a0 = *reinterpret_cast<const float4*>(a + k0);
            float4 a1 = *reinterpret_cast<const float4*>(a + GD + k0);
            float4 a2 = *reinterpret_cast<const float4*>(a + 2 * GD + k0);
            float4 a3 = *reinterpret_cast<const float4*>(a + 3 * GD + k0);
#pragma unroll
            for (int kk = 0; kk < 4; ++kk) {
                float4 w = w4[(k0 + kk) * 24 + q];
                float s0 = ((const float*)&a0)[kk];
                float s1 = ((const float*)&a1)[kk];
                float s2 = ((const float*)&a2)[kk];
                float s3 = ((const float*)&a3)[kk];
                acc0.x += s0 * w.x; acc0.y += s0 * w.y; acc0.z += s0 * w.z; acc0.w += s0 * w.w;
                acc1.x += s1 * w.x; acc1.y += s1 * w.y; acc1.z += s1 * w.z; acc1.w += s1 * w.w;
                acc2.x += s2 * w.x; acc2.y += s2 * w.y; acc2.z += s2 * w.z; acc2.w += s2 * w.w;
                acc3.x += s3 * w.x; acc3.y += s3 * w.y; acc3.z += s3 * w.z; acc3.w += s3 * w.w;
            }
        }
        float4* O4 = reinterpret_cast<float4*>(O);
        O4[(size_t)(r0 + 0) * 24 + q] = acc0;
        O4[(size_t)(r0 + 1) * 24 + q] = acc1;
        O4[(size_t)(r0 + 2) * 24 + q] = acc2;
        O4[(size_t)(r0 + 3) * 24 + q] = acc3;
    }
}

// H[n, q*4..q*4+3] = relu( sum_e vals[e] * T[col[e], q*4..] ), one float4 per thread
__global__ void spmm_relu_k(const int* __restrict__ rp, const int2* __restrict__ ep,
                            const float* __restrict__ T, float* __restrict__ H) {
    int idx = blockIdx.x * blockDim.x + threadIdx.x;
    if (idx >= GN * 24) return;
    int n = idx / 24;
    int q = idx - n * 24;
    int e0 = rp[n], e1 = rp[n + 1];
    const float4* T4 = reinterpret_cast<const float4*>(T);
    float4 acc = {0, 0, 0, 0};
#pragma unroll 4
    for (int e = e0; e < e1; ++e) {
        int2 p = ep[e];
        float4 t = T4[(size_t)p.x * 24 + q];
        float v = __int_as_float(p.y);
        acc.x += v * t.x; acc.y += v * t.y; acc.z += v * t.z; acc.w += v * t.w;
    }
    float4 r;
    r.x = fmaxf(acc.x, 0.f); r.y = fmaxf(acc.y, 0.f);
    r.z = fmaxf(acc.z, 0.f); r.w = fmaxf(acc.w, 0.f);
    reinterpret_cast<float4*>(H)[idx] = r;
}

// one thread per node: l2-normalize row in place + probs = softmax(out @ wc + bc)
// wc/bc reads are lane-uniform -> scalar loads; dot product all-register.
__global__ __launch_bounds__(64) void norm_cls_k(float* __restrict__ OUT,
                                                 const float* __restrict__ WC,
                                                 const float* __restrict__ BC,
                                                 float* __restrict__ PROBS) {
    int n = blockIdx.x * 64 + threadIdx.x;
    if (n >= GN) return;
    const float4* row4 = reinterpret_cast<const float4*>(OUT + (size_t)n * GD);

    float4 r[24];
#pragma unroll
    for (int i = 0; i < 24; ++i) r[i] = row4[i];

    float acc[GC];
#pragma unroll
    for (int c = 0; c < GC; ++c) acc[c] = 0.f;
    float ss = 0.f;
#pragma unroll
    for (int k0 = 0; k0 < 24; ++k0) {
        float4 a = r[k0];
#pragma unroll
        for (int kk = 0; kk < 4; ++kk) {
            float av = ((const float*)&a)[kk];
            ss += av * av;
            const float* wrow = WC + (k0 * 4 + kk) * GC;   // lane-uniform
#pragma unroll
            for (int c = 0; c < GC; ++c) acc[c] += av * wrow[c];
        }
    }
    float scale = rsqrtf(fmaxf(ss, L2EPS));

    float4* orow = reinterpret_cast<float4*>(OUT + (size_t)n * GD);
#pragma unroll
    for (int i = 0; i < 24; ++i) {
        float4 v = r[i];
        v.x *= scale; v.y *= scale; v.z *= scale; v.w *= scale;
        orow[i] = v;
    }

    float m = -1e30f;
#pragma unroll
    for (int c = 0; c < GC; ++c) {
        acc[c] = acc[c] * scale + BC[c];
        m = fmaxf(m, acc[c]);
    }
    float sum = 0.f;
#pragma unroll
    for (int c = 0; c < GC; ++c) {
        acc[c] = __expf(acc[c] - m);
        sum += acc[c];
    }
    float inv = 1.f / sum;
    float4* prow = reinterpret_cast<float4*>(PROBS + (size_t)n * GC);
#pragma unroll
    for (int i = 0; i < 10; ++i) {
        float4 p;
        p.x = acc[i * 4 + 0] * inv;
        p.y = acc[i * 4 + 1] * inv;
        p.z = acc[i * 4 + 2] * inv;
        p.w = acc[i * 4 + 3] * inv;
        prow[i] = p;
    }
}

extern "C" void kernel_launch(void* const* d_in, const int* in_sizes, int n_in,
                              void* d_out, int out_size, void* d_ws, size_t ws_size,
                              hipStream_t stream) {
    const int*   row  = (const int*)d_in[0];
    const int*   col  = (const int*)d_in[1];
    const float* vals = (const float*)d_in[2];
    const float* x    = (const float*)d_in[3];
    const float* w1   = (const float*)d_in[4];
    const float* w2   = (const float*)d_in[5];
    const float* wc   = (const float*)d_in[6];
    const float* bc   = (const float*)d_in[7];

    float* out   = (float*)d_out;                 // [N, D]
    float* probs = out + (size_t)GN * GD;         // [N, C]

    char*  ws  = (char*)d_ws;
    int*   rp  = (int*)ws;                                        // (N+1) ints
    size_t off = (((size_t)(GN + 1) * 4) + 511) & ~(size_t)511;
    float* buf = (float*)(ws + off);                              // [N, D]
    off += (size_t)GN * GD * 4;
    off = (off + 511) & ~(size_t)511;
    int2* ep   = (int2*)(ws + off);                               // [E] packed edges

    // CSR row pointers + packed edges, one kernel
    prep_k<<<(GE + 255) / 256, 256, 0, stream>>>(row, col, vals, rp, ep);
    // t1 = x @ w1
    gemm96_k<<<1172, 256, 0, stream>>>(x, w1, buf);
    // h1 = relu(A @ t1) -> d_out
    spmm_relu_k<<<(GN * 24 + 255) / 256, 256, 0, stream>>>(rp, ep, buf, out);
    // t2 = h1 @ w2
    gemm96_k<<<1172, 256, 0, stream>>>(out, w2, buf);
    // h2 = relu(A @ t2) -> d_out
    spmm_relu_k<<<(GN * 24 + 255) / 256, 256, 0, stream>>>(rp, ep, buf, out);
    // normalize + classifier, one thread per node
    norm_cls_k<<<(GN + 63) / 64, 64, 0, stream>>>(out, wc, bc, probs);
}

// Round 4
// 177.533 us; speedup vs baseline: 2.4674x; 1.0743x over previous
//
#include <hip/hip_runtime.h>
#include <hip/hip_bf16.h>

#define GN 50000
#define GE 800000
#define GD 96
#define GC 40
#define L2EPS 1e-12f

// merged: rp[i] = lower_bound(row, i) for i<=GN ; ep[e] = (col[e], vals[e])
__global__ void prep_k(const int* __restrict__ row, const int* __restrict__ col,
                       const float* __restrict__ vals, int* __restrict__ rp,
                       int2* __restrict__ ep) {
    int i = blockIdx.x * blockDim.x + threadIdx.x;
    if (i < GE) ep[i] = make_int2(col[i], __float_as_int(vals[i]));
    if (i <= GN) {
        int lo = 0, hi = GE;
        while (lo < hi) {
            int mid = (lo + hi) >> 1;
            if (row[mid] < i) lo = mid + 1; else hi = mid;
        }
        rp[i] = lo;
    }
}

// O[N,96] = A[N,96] @ W[96,96]; 4 rows x 4 cols per thread, W in LDS as float4[96][24]
__global__ void gemm96_k(const float* __restrict__ A, const float* __restrict__ W,
                         float* __restrict__ O) {
    __shared__ float4 w4[GD * 24];
    const float4* W4 = reinterpret_cast<const float4*>(W);
    for (int i = threadIdx.x; i < GD * 24; i += blockDim.x) w4[i] = W4[i];
    __syncthreads();
    const int total = (GN / 4) * 24;
    for (int idx = blockIdx.x * blockDim.x + threadIdx.x; idx < total;
         idx += gridDim.x * blockDim.x) {
        int rq = idx / 24;
        int q  = idx - rq * 24;
        int r0 = rq * 4;
        const float* a = A + (size_t)r0 * GD;
        float4 acc0 = {0,0,0,0}, acc1 = {0,0,0,0}, acc2 = {0,0,0,0}, acc3 = {0,0,0,0};
        for (int k0 = 0; k0 < GD; k0 += 4) {
            float4 a0 = *reinterpret_cast<const float4*>(a + k0);
            float4 a1 = *reinterpret_cast<const float4*>(a + GD + k0);
            float4 a2 = *reinterpret_cast<const float4*>(a + 2 * GD + k0);
            float4 a3 = *reinterpret_cast<const float4*>(a + 3 * GD + k0);
#pragma unroll
            for (int kk = 0; kk < 4; ++kk) {
                float4 w = w4[(k0 + kk) * 24 + q];
                float s0 = ((const float*)&a0)[kk];
                float s1 = ((const float*)&a1)[kk];
                float s2 = ((const float*)&a2)[kk];
                float s3 = ((const float*)&a3)[kk];
                acc0.x += s0 * w.x; acc0.y += s0 * w.y; acc0.z += s0 * w.z; acc0.w += s0 * w.w;
                acc1.x += s1 * w.x; acc1.y += s1 * w.y; acc1.z += s1 * w.z; acc1.w += s1 * w.w;
                acc2.x += s2 * w.x; acc2.y += s2 * w.y; acc2.z += s2 * w.z; acc2.w += s2 * w.w;
                acc3.x += s3 * w.x; acc3.y += s3 * w.y; acc3.z += s3 * w.z; acc3.w += s3 * w.w;
            }
        }
        float4* O4 = reinterpret_cast<float4*>(O);
        O4[(size_t)(r0 + 0) * 24 + q] = acc0;
        O4[(size_t)(r0 + 1) * 24 + q] = acc1;
        O4[(size_t)(r0 + 2) * 24 + q] = acc2;
        O4[(size_t)(r0 + 3) * 24 + q] = acc3;
    }
}

// 8 threads per node; thread owns 3 float4 columns (12 floats).
// H[n, t*12 .. t*12+11] = relu( sum_e val[e] * T[col[e], ...] )
__global__ void spmm_relu_k(const int* __restrict__ rp, const int2* __restrict__ ep,
                            const float* __restrict__ T, float* __restrict__ H) {
    int idx = blockIdx.x * blockDim.x + threadIdx.x;
    int n = idx >> 3;
    int t = idx & 7;
    if (n >= GN) return;
    int e0 = rp[n], e1 = rp[n + 1];
    const float4* T4 = reinterpret_cast<const float4*>(T);
    float4 a0 = {0,0,0,0}, a1 = {0,0,0,0}, a2 = {0,0,0,0};
#pragma unroll 2
    for (int e = e0; e < e1; ++e) {
        int2 p = ep[e];
        float v = __int_as_float(p.y);
        const float4* tr = T4 + (size_t)p.x * 24 + t * 3;
        float4 t0 = tr[0], t1 = tr[1], t2 = tr[2];
        a0.x += v * t0.x; a0.y += v * t0.y; a0.z += v * t0.z; a0.w += v * t0.w;
        a1.x += v * t1.x; a1.y += v * t1.y; a1.z += v * t1.z; a1.w += v * t1.w;
        a2.x += v * t2.x; a2.y += v * t2.y; a2.z += v * t2.z; a2.w += v * t2.w;
    }
    float4* hr = reinterpret_cast<float4*>(H) + (size_t)n * 24 + t * 3;
    float4 r0, r1, r2;
    r0.x = fmaxf(a0.x, 0.f); r0.y = fmaxf(a0.y, 0.f); r0.z = fmaxf(a0.z, 0.f); r0.w = fmaxf(a0.w, 0.f);
    r1.x = fmaxf(a1.x, 0.f); r1.y = fmaxf(a1.y, 0.f); r1.z = fmaxf(a1.z, 0.f); r1.w = fmaxf(a1.w, 0.f);
    r2.x = fmaxf(a2.x, 0.f); r2.y = fmaxf(a2.y, 0.f); r2.z = fmaxf(a2.z, 0.f); r2.w = fmaxf(a2.w, 0.f);
    hr[0] = r0; hr[1] = r1; hr[2] = r2;
}

// same as spmm_relu_k but fuses tf.nn.l2_normalize across the node's 8 lanes
__global__ void spmm_relu_norm_k(const int* __restrict__ rp, const int2* __restrict__ ep,
                                 const float* __restrict__ T, float* __restrict__ H) {
    int idx = blockIdx.x * blockDim.x + threadIdx.x;
    int n = idx >> 3;
    int t = idx & 7;
    if (n >= GN) return;
    int e0 = rp[n], e1 = rp[n + 1];
    const float4* T4 = reinterpret_cast<const float4*>(T);
    float4 a0 = {0,0,0,0}, a1 = {0,0,0,0}, a2 = {0,0,0,0};
#pragma unroll 2
    for (int e = e0; e < e1; ++e) {
        int2 p = ep[e];
        float v = __int_as_float(p.y);
        const float4* tr = T4 + (size_t)p.x * 24 + t * 3;
        float4 t0 = tr[0], t1 = tr[1], t2 = tr[2];
        a0.x += v * t0.x; a0.y += v * t0.y; a0.z += v * t0.z; a0.w += v * t0.w;
        a1.x += v * t1.x; a1.y += v * t1.y; a1.z += v * t1.z; a1.w += v * t1.w;
        a2.x += v * t2.x; a2.y += v * t2.y; a2.z += v * t2.z; a2.w += v * t2.w;
    }
    a0.x = fmaxf(a0.x, 0.f); a0.y = fmaxf(a0.y, 0.f); a0.z = fmaxf(a0.z, 0.f); a0.w = fmaxf(a0.w, 0.f);
    a1.x = fmaxf(a1.x, 0.f); a1.y = fmaxf(a1.y, 0.f); a1.z = fmaxf(a1.z, 0.f); a1.w = fmaxf(a1.w, 0.f);
    a2.x = fmaxf(a2.x, 0.f); a2.y = fmaxf(a2.y, 0.f); a2.z = fmaxf(a2.z, 0.f); a2.w = fmaxf(a2.w, 0.f);
    float ss = a0.x*a0.x + a0.y*a0.y + a0.z*a0.z + a0.w*a0.w
             + a1.x*a1.x + a1.y*a1.y + a1.z*a1.z + a1.w*a1.w
             + a2.x*a2.x + a2.y*a2.y + a2.z*a2.z + a2.w*a2.w;
    // reduce across the node's 8 lanes (lane groups 8-aligned)
    ss += __shfl_xor(ss, 1);
    ss += __shfl_xor(ss, 2);
    ss += __shfl_xor(ss, 4);
    float s = rsqrtf(fmaxf(ss, L2EPS));
    a0.x *= s; a0.y *= s; a0.z *= s; a0.w *= s;
    a1.x *= s; a1.y *= s; a1.z *= s; a1.w *= s;
    a2.x *= s; a2.y *= s; a2.z *= s; a2.w *= s;
    float4* hr = reinterpret_cast<float4*>(H) + (size_t)n * 24 + t * 3;
    hr[0] = a0; hr[1] = a1; hr[2] = a2;
}

// logits[N,40] = A[N,96] @ WC[96,40] + bc; 4 rows x 4 cols per thread, WC in LDS
__global__ void cls_gemm_k(const float* __restrict__ A, const float* __restrict__ WC,
                           const float* __restrict__ BC, float* __restrict__ L) {
    __shared__ float4 w4[GD * 10];
    const float4* W4 = reinterpret_cast<const float4*>(WC);
    for (int i = threadIdx.x; i < GD * 10; i += blockDim.x) w4[i] = W4[i];
    __syncthreads();
    int idx = blockIdx.x * blockDim.x + threadIdx.x;
    if (idx >= (GN / 4) * 10) return;
    int rq = idx / 10;
    int q  = idx - rq * 10;
    int r0 = rq * 4;
    const float* a = A + (size_t)r0 * GD;
    float4 acc0 = {0,0,0,0}, acc1 = {0,0,0,0}, acc2 = {0,0,0,0}, acc3 = {0,0,0,0};
    for (int k0 = 0; k0 < GD; k0 += 4) {
        float4 a0 = *reinterpret_cast<const float4*>(a + k0);
        float4 a1 = *reinterpret_cast<const float4*>(a + GD + k0);
        float4 a2 = *reinterpret_cast<const float4*>(a + 2 * GD + k0);
        float4 a3 = *reinterpret_cast<const float4*>(a + 3 * GD + k0);
#pragma unroll
        for (int kk = 0; kk < 4; ++kk) {
            float4 w = w4[(k0 + kk) * 10 + q];
            float s0 = ((const float*)&a0)[kk];
            float s1 = ((const float*)&a1)[kk];
            float s2 = ((const float*)&a2)[kk];
            float s3 = ((const float*)&a3)[kk];
            acc0.x += s0 * w.x; acc0.y += s0 * w.y; acc0.z += s0 * w.z; acc0.w += s0 * w.w;
            acc1.x += s1 * w.x; acc1.y += s1 * w.y; acc1.z += s1 * w.z; acc1.w += s1 * w.w;
            acc2.x += s2 * w.x; acc2.y += s2 * w.y; acc2.z += s2 * w.z; acc2.w += s2 * w.w;
            acc3.x += s3 * w.x; acc3.y += s3 * w.y; acc3.z += s3 * w.z; acc3.w += s3 * w.w;
        }
    }
    float4 b = *reinterpret_cast<const float4*>(BC + q * 4);
    acc0.x += b.x; acc0.y += b.y; acc0.z += b.z; acc0.w += b.w;
    acc1.x += b.x; acc1.y += b.y; acc1.z += b.z; acc1.w += b.w;
    acc2.x += b.x; acc2.y += b.y; acc2.z += b.z; acc2.w += b.w;
    acc3.x += b.x; acc3.y += b.y; acc3.z += b.z; acc3.w += b.w;
    float4* L4 = reinterpret_cast<float4*>(L);
    L4[(size_t)(r0 + 0) * 10 + q] = acc0;
    L4[(size_t)(r0 + 1) * 10 + q] = acc1;
    L4[(size_t)(r0 + 2) * 10 + q] = acc2;
    L4[(size_t)(r0 + 3) * 10 + q] = acc3;
}

// thread per node: softmax over 40 logits (10 independent float4 loads -> ILP)
__global__ void softmax_k(const float* __restrict__ L, float* __restrict__ PROBS) {
    int n = blockIdx.x * blockDim.x + threadIdx.x;
    if (n >= GN) return;
    const float4* lr = reinterpret_cast<const float4*>(L + (size_t)n * GC);
    float4 v[10];
#pragma unroll
    for (int i = 0; i < 10; ++i) v[i] = lr[i];
    float m = -1e30f;
#pragma unroll
    for (int i = 0; i < 10; ++i)
        m = fmaxf(m, fmaxf(fmaxf(v[i].x, v[i].y), fmaxf(v[i].z, v[i].w)));
    float sum = 0.f;
#pragma unroll
    for (int i = 0; i < 10; ++i) {
        v[i].x = __expf(v[i].x - m); v[i].y = __expf(v[i].y - m);
        v[i].z = __expf(v[i].z - m); v[i].w = __expf(v[i].w - m);
        sum += v[i].x + v[i].y + v[i].z + v[i].w;
    }
    float inv = 1.f / sum;
    float4* pr = reinterpret_cast<float4*>(PROBS + (size_t)n * GC);
#pragma unroll
    for (int i = 0; i < 10; ++i) {
        v[i].x *= inv; v[i].y *= inv; v[i].z *= inv; v[i].w *= inv;
        pr[i] = v[i];
    }
}

extern "C" void kernel_launch(void* const* d_in, const int* in_sizes, int n_in,
                              void* d_out, int out_size, void* d_ws, size_t ws_size,
                              hipStream_t stream) {
    const int*   row  = (const int*)d_in[0];
    const int*   col  = (const int*)d_in[1];
    const float* vals = (const float*)d_in[2];
    const float* x    = (const float*)d_in[3];
    const float* w1   = (const float*)d_in[4];
    const float* w2   = (const float*)d_in[5];
    const float* wc   = (const float*)d_in[6];
    const float* bc   = (const float*)d_in[7];

    float* out   = (float*)d_out;                 // [N, D]
    float* probs = out + (size_t)GN * GD;         // [N, C]

    char*  ws  = (char*)d_ws;
    int*   rp  = (int*)ws;                                        // (N+1) ints
    size_t off = (((size_t)(GN + 1) * 4) + 511) & ~(size_t)511;
    float* buf = (float*)(ws + off);                              // [N,D]; reused as logits [N,C]
    off += (size_t)GN * GD * 4;
    off = (off + 511) & ~(size_t)511;
    int2* ep   = (int2*)(ws + off);                               // [E] packed edges

    prep_k<<<(GE + 255) / 256, 256, 0, stream>>>(row, col, vals, rp, ep);
    // t1 = x @ w1
    gemm96_k<<<1172, 256, 0, stream>>>(x, w1, buf);
    // h1 = relu(A @ t1) -> d_out
    spmm_relu_k<<<(GN * 8 + 255) / 256, 256, 0, stream>>>(rp, ep, buf, out);
    // t2 = h1 @ w2
    gemm96_k<<<1172, 256, 0, stream>>>(out, w2, buf);
    // out = l2norm(relu(A @ t2))
    spmm_relu_norm_k<<<(GN * 8 + 255) / 256, 256, 0, stream>>>(rp, ep, buf, out);
    // logits = out @ wc + bc -> buf ; probs = softmax(logits)
    cls_gemm_k<<<((GN / 4) * 10 + 255) / 256, 256, 0, stream>>>(out, wc, bc, buf);
    softmax_k<<<(GN + 255) / 256, 256, 0, stream>>>(buf, probs);
}

// Round 5
// 147.953 us; speedup vs baseline: 2.9607x; 1.1999x over previous
//
#include <hip/hip_runtime.h>
#include <hip/hip_bf16.h>

#define GN 50000
#define GE 800000
#define GD 96
#define GC 40
#define L2EPS 1e-12f

__device__ __forceinline__ unsigned f2bf(float x) {           // RNE float->bf16 bits
    union { float f; unsigned u; } v; v.f = x;
    return (v.u + 0x7fffu + ((v.u >> 16) & 1u)) >> 16;
}
__device__ __forceinline__ float bflo(unsigned u) { return __uint_as_float(u << 16); }
__device__ __forceinline__ float bfhi(unsigned u) { return __uint_as_float(u & 0xffff0000u); }

// merged: rp[i] = lower_bound(row, i) for i<=GN ; ep[e] = (col[e], vals[e])
__global__ void prep_k(const int* __restrict__ row, const int* __restrict__ col,
                       const float* __restrict__ vals, int* __restrict__ rp,
                       int2* __restrict__ ep) {
    int i = blockIdx.x * blockDim.x + threadIdx.x;
    if (i < GE) ep[i] = make_int2(col[i], __float_as_int(vals[i]));
    if (i <= GN) {
        int lo = 0, hi = GE;
        while (lo < hi) {
            int mid = (lo + hi) >> 1;
            if (row[mid] < i) lo = mid + 1; else hi = mid;
        }
        rp[i] = lo;
    }
}

// O_bf16[N,96] = A_f32[N,96] @ W[96,96]; 4 rows x 4 cols per thread, W in LDS
__global__ void gemm96_k(const float* __restrict__ A, const float* __restrict__ W,
                         unsigned* __restrict__ O) {     // O: bf16 pairs, 48 uints/row
    __shared__ float4 w4[GD * 24];
    const float4* W4 = reinterpret_cast<const float4*>(W);
    for (int i = threadIdx.x; i < GD * 24; i += blockDim.x) w4[i] = W4[i];
    __syncthreads();
    const int total = (GN / 4) * 24;
    for (int idx = blockIdx.x * blockDim.x + threadIdx.x; idx < total;
         idx += gridDim.x * blockDim.x) {
        int rq = idx / 24;
        int q  = idx - rq * 24;
        int r0 = rq * 4;
        const float* a = A + (size_t)r0 * GD;
        float4 acc0 = {0,0,0,0}, acc1 = {0,0,0,0}, acc2 = {0,0,0,0}, acc3 = {0,0,0,0};
        for (int k0 = 0; k0 < GD; k0 += 4) {
            float4 a0 = *reinterpret_cast<const float4*>(a + k0);
            float4 a1 = *reinterpret_cast<const float4*>(a + GD + k0);
            float4 a2 = *reinterpret_cast<const float4*>(a + 2 * GD + k0);
            float4 a3 = *reinterpret_cast<const float4*>(a + 3 * GD + k0);
#pragma unroll
            for (int kk = 0; kk < 4; ++kk) {
                float4 w = w4[(k0 + kk) * 24 + q];
                float s0 = ((const float*)&a0)[kk];
                float s1 = ((const float*)&a1)[kk];
                float s2 = ((const float*)&a2)[kk];
                float s3 = ((const float*)&a3)[kk];
                acc0.x += s0 * w.x; acc0.y += s0 * w.y; acc0.z += s0 * w.z; acc0.w += s0 * w.w;
                acc1.x += s1 * w.x; acc1.y += s1 * w.y; acc1.z += s1 * w.z; acc1.w += s1 * w.w;
                acc2.x += s2 * w.x; acc2.y += s2 * w.y; acc2.z += s2 * w.z; acc2.w += s2 * w.w;
                acc3.x += s3 * w.x; acc3.y += s3 * w.y; acc3.z += s3 * w.z; acc3.w += s3 * w.w;
            }
        }
        // pack 4 f32 -> 2 uints (4 bf16) per row; row stride = 48 uints
        uint2* O2 = reinterpret_cast<uint2*>(O);
        uint2 p0 = make_uint2(f2bf(acc0.x) | (f2bf(acc0.y) << 16), f2bf(acc0.z) | (f2bf(acc0.w) << 16));
        uint2 p1 = make_uint2(f2bf(acc1.x) | (f2bf(acc1.y) << 16), f2bf(acc1.z) | (f2bf(acc1.w) << 16));
        uint2 p2 = make_uint2(f2bf(acc2.x) | (f2bf(acc2.y) << 16), f2bf(acc2.z) | (f2bf(acc2.w) << 16));
        uint2 p3 = make_uint2(f2bf(acc3.x) | (f2bf(acc3.y) << 16), f2bf(acc3.z) | (f2bf(acc3.w) << 16));
        O2[(size_t)(r0 + 0) * 24 + q] = p0;
        O2[(size_t)(r0 + 1) * 24 + q] = p1;
        O2[(size_t)(r0 + 2) * 24 + q] = p2;
        O2[(size_t)(r0 + 3) * 24 + q] = p3;
    }
}

// 8 threads/node. Thread t owns cols [8t..8t+7] and [64+4t..64+4t+3] (12 floats).
// Gather rows of Tb (bf16, 48 uints/row): uint4 @ t*16B + uint2 @ 128B+t*8B.
#define SPMM_BODY(POST)                                                              \
    int idx = blockIdx.x * blockDim.x + threadIdx.x;                                 \
    int n = idx >> 3;                                                                \
    int t = idx & 7;                                                                 \
    if (n >= GN) return;                                                             \
    int e0 = rp[n], e1 = rp[n + 1];                                                  \
    const unsigned* base = Tb;                                                       \
    float a0=0,a1=0,a2=0,a3=0,a4=0,a5=0,a6=0,a7=0,a8=0,a9=0,a10=0,a11=0;             \
    _Pragma("unroll 2")                                                              \
    for (int e = e0; e < e1; ++e) {                                                  \
        int2 p = ep[e];                                                              \
        float v = __int_as_float(p.y);                                               \
        const unsigned* r = base + (size_t)p.x * 48;                                 \
        uint4 u = *reinterpret_cast<const uint4*>(r + t * 4);                        \
        uint2 w = *reinterpret_cast<const uint2*>(r + 32 + t * 2);                   \
        a0 += v * bflo(u.x); a1 += v * bfhi(u.x);                                    \
        a2 += v * bflo(u.y); a3 += v * bfhi(u.y);                                    \
        a4 += v * bflo(u.z); a5 += v * bfhi(u.z);                                    \
        a6 += v * bflo(u.w); a7 += v * bfhi(u.w);                                    \
        a8 += v * bflo(w.x); a9 += v * bfhi(w.x);                                    \
        a10 += v * bflo(w.y); a11 += v * bfhi(w.y);                                  \
    }                                                                                \
    a0=fmaxf(a0,0.f); a1=fmaxf(a1,0.f); a2=fmaxf(a2,0.f); a3=fmaxf(a3,0.f);          \
    a4=fmaxf(a4,0.f); a5=fmaxf(a5,0.f); a6=fmaxf(a6,0.f); a7=fmaxf(a7,0.f);          \
    a8=fmaxf(a8,0.f); a9=fmaxf(a9,0.f); a10=fmaxf(a10,0.f); a11=fmaxf(a11,0.f);      \
    POST                                                                             \
    float4* hr = reinterpret_cast<float4*>(H + (size_t)n * GD + t * 8);              \
    hr[0] = make_float4(a0, a1, a2, a3);                                             \
    hr[1] = make_float4(a4, a5, a6, a7);                                             \
    *reinterpret_cast<float4*>(H + (size_t)n * GD + 64 + t * 4) =                    \
        make_float4(a8, a9, a10, a11);

__global__ void spmm_relu_k(const int* __restrict__ rp, const int2* __restrict__ ep,
                            const unsigned* __restrict__ Tb, float* __restrict__ H) {
    SPMM_BODY(;)
}

__global__ void spmm_relu_norm_k(const int* __restrict__ rp, const int2* __restrict__ ep,
                                 const unsigned* __restrict__ Tb, float* __restrict__ H) {
    SPMM_BODY(
        float ss = a0*a0+a1*a1+a2*a2+a3*a3+a4*a4+a5*a5+a6*a6+a7*a7+a8*a8+a9*a9+a10*a10+a11*a11;
        ss += __shfl_xor(ss, 1);
        ss += __shfl_xor(ss, 2);
        ss += __shfl_xor(ss, 4);
        float s = rsqrtf(fmaxf(ss, L2EPS));
        a0*=s; a1*=s; a2*=s; a3*=s; a4*=s; a5*=s;
        a6*=s; a7*=s; a8*=s; a9*=s; a10*=s; a11*=s;
    )
}

// logits[N,40] = A[N,96] @ WC[96,40] + bc; 4 rows x 4 cols per thread, WC in LDS
__global__ void cls_gemm_k(const float* __restrict__ A, const float* __restrict__ WC,
                           const float* __restrict__ BC, float* __restrict__ L) {
    __shared__ float4 w4[GD * 10];
    const float4* W4 = reinterpret_cast<const float4*>(WC);
    for (int i = threadIdx.x; i < GD * 10; i += blockDim.x) w4[i] = W4[i];
    __syncthreads();
    int idx = blockIdx.x * blockDim.x + threadIdx.x;
    if (idx >= (GN / 4) * 10) return;
    int rq = idx / 10;
    int q  = idx - rq * 10;
    int r0 = rq * 4;
    const float* a = A + (size_t)r0 * GD;
    float4 acc0 = {0,0,0,0}, acc1 = {0,0,0,0}, acc2 = {0,0,0,0}, acc3 = {0,0,0,0};
    for (int k0 = 0; k0 < GD; k0 += 4) {
        float4 a0 = *reinterpret_cast<const float4*>(a + k0);
        float4 a1 = *reinterpret_cast<const float4*>(a + GD + k0);
        float4 a2 = *reinterpret_cast<const float4*>(a + 2 * GD + k0);
        float4 a3 = *reinterpret_cast<const float4*>(a + 3 * GD + k0);
#pragma unroll
        for (int kk = 0; kk < 4; ++kk) {
            float4 w = w4[(k0 + kk) * 10 + q];
            float s0 = ((const float*)&a0)[kk];
            float s1 = ((const float*)&a1)[kk];
            float s2 = ((const float*)&a2)[kk];
            float s3 = ((const float*)&a3)[kk];
            acc0.x += s0 * w.x; acc0.y += s0 * w.y; acc0.z += s0 * w.z; acc0.w += s0 * w.w;
            acc1.x += s1 * w.x; acc1.y += s1 * w.y; acc1.z += s1 * w.z; acc1.w += s1 * w.w;
            acc2.x += s2 * w.x; acc2.y += s2 * w.y; acc2.z += s2 * w.z; acc2.w += s2 * w.w;
            acc3.x += s3 * w.x; acc3.y += s3 * w.y; acc3.z += s3 * w.z; acc3.w += s3 * w.w;
        }
    }
    float4 b = *reinterpret_cast<const float4*>(BC + q * 4);
    acc0.x += b.x; acc0.y += b.y; acc0.z += b.z; acc0.w += b.w;
    acc1.x += b.x; acc1.y += b.y; acc1.z += b.z; acc1.w += b.w;
    acc2.x += b.x; acc2.y += b.y; acc2.z += b.z; acc2.w += b.w;
    acc3.x += b.x; acc3.y += b.y; acc3.z += b.z; acc3.w += b.w;
    float4* L4 = reinterpret_cast<float4*>(L);
    L4[(size_t)(r0 + 0) * 10 + q] = acc0;
    L4[(size_t)(r0 + 1) * 10 + q] = acc1;
    L4[(size_t)(r0 + 2) * 10 + q] = acc2;
    L4[(size_t)(r0 + 3) * 10 + q] = acc3;
}

// thread per node: softmax over 40 logits
__global__ void softmax_k(const float* __restrict__ L, float* __restrict__ PROBS) {
    int n = blockIdx.x * blockDim.x + threadIdx.x;
    if (n >= GN) return;
    const float4* lr = reinterpret_cast<const float4*>(L + (size_t)n * GC);
    float4 v[10];
#pragma unroll
    for (int i = 0; i < 10; ++i) v[i] = lr[i];
    float m = -1e30f;
#pragma unroll
    for (int i = 0; i < 10; ++i)
        m = fmaxf(m, fmaxf(fmaxf(v[i].x, v[i].y), fmaxf(v[i].z, v[i].w)));
    float sum = 0.f;
#pragma unroll
    for (int i = 0; i < 10; ++i) {
        v[i].x = __expf(v[i].x - m); v[i].y = __expf(v[i].y - m);
        v[i].z = __expf(v[i].z - m); v[i].w = __expf(v[i].w - m);
        sum += v[i].x + v[i].y + v[i].z + v[i].w;
    }
    float inv = 1.f / sum;
    float4* pr = reinterpret_cast<float4*>(PROBS + (size_t)n * GC);
#pragma unroll
    for (int i = 0; i < 10; ++i) {
        v[i].x *= inv; v[i].y *= inv; v[i].z *= inv; v[i].w *= inv;
        pr[i] = v[i];
    }
}

extern "C" void kernel_launch(void* const* d_in, const int* in_sizes, int n_in,
                              void* d_out, int out_size, void* d_ws, size_t ws_size,
                              hipStream_t stream) {
    const int*   row  = (const int*)d_in[0];
    const int*   col  = (const int*)d_in[1];
    const float* vals = (const float*)d_in[2];
    const float* x    = (const float*)d_in[3];
    const float* w1   = (const float*)d_in[4];
    const float* w2   = (const float*)d_in[5];
    const float* wc   = (const float*)d_in[6];
    const float* bc   = (const float*)d_in[7];

    float* out   = (float*)d_out;                 // [N, D]
    float* probs = out + (size_t)GN * GD;         // [N, C]

    char*  ws  = (char*)d_ws;
    int*   rp  = (int*)ws;                                        // (N+1) ints
    size_t off = (((size_t)(GN + 1) * 4) + 511) & ~(size_t)511;
    unsigned* buf = (unsigned*)(ws + off);        // bf16 [N,96] (48 uints/row); reused as f32 logits [N,40]
    off += (size_t)GN * GD * 4;                   // keep old (larger) reservation
    off = (off + 511) & ~(size_t)511;
    int2* ep   = (int2*)(ws + off);               // [E] packed edges

    prep_k<<<(GE + 255) / 256, 256, 0, stream>>>(row, col, vals, rp, ep);
    // t1 = bf16(x @ w1)
    gemm96_k<<<1172, 256, 0, stream>>>(x, w1, buf);
    // h1 = relu(A @ t1) -> d_out (f32)
    spmm_relu_k<<<(GN * 8 + 255) / 256, 256, 0, stream>>>(rp, ep, buf, out);
    // t2 = bf16(h1 @ w2)
    gemm96_k<<<1172, 256, 0, stream>>>(out, w2, buf);
    // out = l2norm(relu(A @ t2))
    spmm_relu_norm_k<<<(GN * 8 + 255) / 256, 256, 0, stream>>>(rp, ep, buf, out);
    // logits = out @ wc + bc -> buf (f32) ; probs = softmax(logits)
    cls_gemm_k<<<((GN / 4) * 10 + 255) / 256, 256, 0, stream>>>(out, wc, bc, (float*)buf);
    softmax_k<<<(GN + 255) / 256, 256, 0, stream>>>((float*)buf, probs);
}

// Round 6
// 113.269 us; speedup vs baseline: 3.8674x; 1.3062x over previous
//
#include <hip/hip_runtime.h>
#include <hip/hip_bf16.h>

#define GN 50000
#define GE 800000
#define GD 96
#define GC 40
#define L2EPS 1e-12f

typedef __attribute__((ext_vector_type(8))) short short8v;   // 8 bf16 = 4 VGPR
typedef __attribute__((ext_vector_type(4))) float f32x4;

__device__ __forceinline__ unsigned f2bf(float x) {           // RNE float->bf16 bits
    union { float f; unsigned u; } v; v.f = x;
    return (v.u + 0x7fffu + ((v.u >> 16) & 1u)) >> 16;
}
__device__ __forceinline__ float bflo(unsigned u) { return __uint_as_float(u << 16); }
__device__ __forceinline__ float bfhi(unsigned u) { return __uint_as_float(u & 0xffff0000u); }

// merged: rp[i] = lower_bound(row, i) for i<=GN ; ep[e] = (col[e], vals[e])
__global__ void prep_k(const int* __restrict__ row, const int* __restrict__ col,
                       const float* __restrict__ vals, int* __restrict__ rp,
                       int2* __restrict__ ep) {
    int i = blockIdx.x * blockDim.x + threadIdx.x;
    if (i < GE) ep[i] = make_int2(col[i], __float_as_int(vals[i]));
    if (i <= GN) {
        int lo = 0, hi = GE;
        while (lo < hi) {
            int mid = (lo + hi) >> 1;
            if (row[mid] < i) lo = mid + 1; else hi = mid;
        }
        rp[i] = lo;
    }
}

// pack W[96][96] f32 -> MFMA B-fragment bf16 layout:
// Wb[frag=nt*3+kt][lane][r] (uint, 2 bf16) ; element j=2r(+1): W[kt*32+(lane>>4)*8+j][nt*16+(lane&15)]
__global__ void wpack_k(const float* __restrict__ w1, const float* __restrict__ w2,
                        unsigned* __restrict__ Wb1, unsigned* __restrict__ Wb2) {
    int idx = blockIdx.x * blockDim.x + threadIdx.x;
    if (idx >= 2 * 4608) return;
    const float* W = (idx < 4608) ? w1 : w2;
    unsigned* Wb   = (idx < 4608) ? Wb1 : Wb2;
    int i = (idx < 4608) ? idx : idx - 4608;
    int r = i & 3;
    int lane = (i >> 2) & 63;
    int frag = i >> 8;                 // 0..17
    int nt = frag / 3, kt = frag - nt * 3;
    int col = nt * 16 + (lane & 15);
    int k = kt * 32 + (lane >> 4) * 8 + r * 2;
    Wb[i] = f2bf(W[k * GD + col]) | (f2bf(W[(k + 1) * GD + col]) << 16);
}

// O_bf16[N,96] = A_f32[N,96] @ W ; MFMA 16x16x32 bf16 with split-A (hi+lo -> A exact).
// One wave per 16-row tile; 6 N-tiles x 3 K-frags x 2(hi,lo) = 36 mfma.
__global__ __launch_bounds__(64) void gemm_mfma_k(const float* __restrict__ A,
                                                  const uint4* __restrict__ Wb,
                                                  unsigned short* __restrict__ O) {
    const int tile = blockIdx.x;            // 0..3124
    const int l  = threadIdx.x;             // 0..63
    const int m  = l & 15;                  // A-row within tile / C-col within tile
    const int kg = l >> 4;                  // k-group

    const float* arow = A + (size_t)(tile * 16 + m) * GD + kg * 8;
    short8v ah[3], al[3];
#pragma unroll
    for (int kt = 0; kt < 3; ++kt) {
        const float4* ap = reinterpret_cast<const float4*>(arow + kt * 32);
        float4 x0 = ap[0], x1 = ap[1];
        uint4 H, L;
        H.x = f2bf(x0.x) | (f2bf(x0.y) << 16);
        H.y = f2bf(x0.z) | (f2bf(x0.w) << 16);
        H.z = f2bf(x1.x) | (f2bf(x1.y) << 16);
        H.w = f2bf(x1.z) | (f2bf(x1.w) << 16);
        L.x = f2bf(x0.x - bflo(H.x)) | (f2bf(x0.y - bfhi(H.x)) << 16);
        L.y = f2bf(x0.z - bflo(H.y)) | (f2bf(x0.w - bfhi(H.y)) << 16);
        L.z = f2bf(x1.x - bflo(H.z)) | (f2bf(x1.y - bfhi(H.z)) << 16);
        L.w = f2bf(x1.z - bflo(H.w)) | (f2bf(x1.w - bfhi(H.w)) << 16);
        union { uint4 u; short8v s; } ch, cl;
        ch.u = H; cl.u = L;
        ah[kt] = ch.s; al[kt] = cl.s;
    }

#pragma unroll
    for (int nt = 0; nt < 6; ++nt) {
        f32x4 acc = {0.f, 0.f, 0.f, 0.f};
#pragma unroll
        for (int kt = 0; kt < 3; ++kt) {
            union { uint4 u; short8v s; } b;
            b.u = Wb[(nt * 3 + kt) * 64 + l];
            acc = __builtin_amdgcn_mfma_f32_16x16x32_bf16(ah[kt], b.s, acc, 0, 0, 0);
            acc = __builtin_amdgcn_mfma_f32_16x16x32_bf16(al[kt], b.s, acc, 0, 0, 0);
        }
        // C/D layout: col = l&15 (=m), row = kg*4 + reg
        int ccol = nt * 16 + m;
#pragma unroll
        for (int reg = 0; reg < 4; ++reg) {
            int rrow = tile * 16 + kg * 4 + reg;
            O[(size_t)rrow * GD + ccol] = (unsigned short)f2bf(acc[reg]);
        }
    }
}

// 8 threads/node. Thread t owns cols [8t..8t+7] and [64+4t..64+4t+3] (12 floats).
// Gather rows of Tb (bf16, 48 uints/row): uint4 @ t*16B + uint2 @ 128B+t*8B.
#define SPMM_BODY(POST)                                                              \
    int idx = blockIdx.x * blockDim.x + threadIdx.x;                                 \
    int n = idx >> 3;                                                                \
    int t = idx & 7;                                                                 \
    if (n >= GN) return;                                                             \
    int e0 = rp[n], e1 = rp[n + 1];                                                  \
    const unsigned* base = Tb;                                                       \
    float a0=0,a1=0,a2=0,a3=0,a4=0,a5=0,a6=0,a7=0,a8=0,a9=0,a10=0,a11=0;             \
    _Pragma("unroll 2")                                                              \
    for (int e = e0; e < e1; ++e) {                                                  \
        int2 p = ep[e];                                                              \
        float v = __int_as_float(p.y);                                               \
        const unsigned* r = base + (size_t)p.x * 48;                                 \
        uint4 u = *reinterpret_cast<const uint4*>(r + t * 4);                        \
        uint2 w = *reinterpret_cast<const uint2*>(r + 32 + t * 2);                   \
        a0 += v * bflo(u.x); a1 += v * bfhi(u.x);                                    \
        a2 += v * bflo(u.y); a3 += v * bfhi(u.y);                                    \
        a4 += v * bflo(u.z); a5 += v * bfhi(u.z);                                    \
        a6 += v * bflo(u.w); a7 += v * bfhi(u.w);                                    \
        a8 += v * bflo(w.x); a9 += v * bfhi(w.x);                                    \
        a10 += v * bflo(w.y); a11 += v * bfhi(w.y);                                  \
    }                                                                                \
    a0=fmaxf(a0,0.f); a1=fmaxf(a1,0.f); a2=fmaxf(a2,0.f); a3=fmaxf(a3,0.f);          \
    a4=fmaxf(a4,0.f); a5=fmaxf(a5,0.f); a6=fmaxf(a6,0.f); a7=fmaxf(a7,0.f);          \
    a8=fmaxf(a8,0.f); a9=fmaxf(a9,0.f); a10=fmaxf(a10,0.f); a11=fmaxf(a11,0.f);      \
    POST                                                                             \
    float4* hr = reinterpret_cast<float4*>(H + (size_t)n * GD + t * 8);              \
    hr[0] = make_float4(a0, a1, a2, a3);                                             \
    hr[1] = make_float4(a4, a5, a6, a7);                                             \
    *reinterpret_cast<float4*>(H + (size_t)n * GD + 64 + t * 4) =                    \
        make_float4(a8, a9, a10, a11);

__global__ void spmm_relu_k(const int* __restrict__ rp, const int2* __restrict__ ep,
                            const unsigned* __restrict__ Tb, float* __restrict__ H) {
    SPMM_BODY(;)
}

__global__ void spmm_relu_norm_k(const int* __restrict__ rp, const int2* __restrict__ ep,
                                 const unsigned* __restrict__ Tb, float* __restrict__ H) {
    SPMM_BODY(
        float ss = a0*a0+a1*a1+a2*a2+a3*a3+a4*a4+a5*a5+a6*a6+a7*a7+a8*a8+a9*a9+a10*a10+a11*a11;
        ss += __shfl_xor(ss, 1);
        ss += __shfl_xor(ss, 2);
        ss += __shfl_xor(ss, 4);
        float s = rsqrtf(fmaxf(ss, L2EPS));
        a0*=s; a1*=s; a2*=s; a3*=s; a4*=s; a5*=s;
        a6*=s; a7*=s; a8*=s; a9*=s; a10*=s; a11*=s;
    )
}

// logits[N,40] = A[N,96] @ WC[96,40] + bc; 4 rows x 4 cols per thread, WC in LDS
__global__ void cls_gemm_k(const float* __restrict__ A, const float* __restrict__ WC,
                           const float* __restrict__ BC, float* __restrict__ L) {
    __shared__ float4 w4[GD * 10];
    const float4* W4 = reinterpret_cast<const float4*>(WC);
    for (int i = threadIdx.x; i < GD * 10; i += blockDim.x) w4[i] = W4[i];
    __syncthreads();
    int idx = blockIdx.x * blockDim.x + threadIdx.x;
    if (idx >= (GN / 4) * 10) return;
    int rq = idx / 10;
    int q  = idx - rq * 10;
    int r0 = rq * 4;
    const float* a = A + (size_t)r0 * GD;
    float4 acc0 = {0,0,0,0}, acc1 = {0,0,0,0}, acc2 = {0,0,0,0}, acc3 = {0,0,0,0};
    for (int k0 = 0; k0 < GD; k0 += 4) {
        float4 a0 = *reinterpret_cast<const float4*>(a + k0);
        float4 a1 = *reinterpret_cast<const float4*>(a + GD + k0);
        float4 a2 = *reinterpret_cast<const float4*>(a + 2 * GD + k0);
        float4 a3 = *reinterpret_cast<const float4*>(a + 3 * GD + k0);
#pragma unroll
        for (int kk = 0; kk < 4; ++kk) {
            float4 w = w4[(k0 + kk) * 10 + q];
            float s0 = ((const float*)&a0)[kk];
            float s1 = ((const float*)&a1)[kk];
            float s2 = ((const float*)&a2)[kk];
            float s3 = ((const float*)&a3)[kk];
            acc0.x += s0 * w.x; acc0.y += s0 * w.y; acc0.z += s0 * w.z; acc0.w += s0 * w.w;
            acc1.x += s1 * w.x; acc1.y += s1 * w.y; acc1.z += s1 * w.z; acc1.w += s1 * w.w;
            acc2.x += s2 * w.x; acc2.y += s2 * w.y; acc2.z += s2 * w.z; acc2.w += s2 * w.w;
            acc3.x += s3 * w.x; acc3.y += s3 * w.y; acc3.z += s3 * w.z; acc3.w += s3 * w.w;
        }
    }
    float4 b = *reinterpret_cast<const float4*>(BC + q * 4);
    acc0.x += b.x; acc0.y += b.y; acc0.z += b.z; acc0.w += b.w;
    acc1.x += b.x; acc1.y += b.y; acc1.z += b.z; acc1.w += b.w;
    acc2.x += b.x; acc2.y += b.y; acc2.z += b.z; acc2.w += b.w;
    acc3.x += b.x; acc3.y += b.y; acc3.z += b.z; acc3.w += b.w;
    float4* L4 = reinterpret_cast<float4*>(L);
    L4[(size_t)(r0 + 0) * 10 + q] = acc0;
    L4[(size_t)(r0 + 1) * 10 + q] = acc1;
    L4[(size_t)(r0 + 2) * 10 + q] = acc2;
    L4[(size_t)(r0 + 3) * 10 + q] = acc3;
}

// thread per node: softmax over 40 logits
__global__ void softmax_k(const float* __restrict__ L, float* __restrict__ PROBS) {
    int n = blockIdx.x * blockDim.x + threadIdx.x;
    if (n >= GN) return;
    const float4* lr = reinterpret_cast<const float4*>(L + (size_t)n * GC);
    float4 v[10];
#pragma unroll
    for (int i = 0; i < 10; ++i) v[i] = lr[i];
    float m = -1e30f;
#pragma unroll
    for (int i = 0; i < 10; ++i)
        m = fmaxf(m, fmaxf(fmaxf(v[i].x, v[i].y), fmaxf(v[i].z, v[i].w)));
    float sum = 0.f;
#pragma unroll
    for (int i = 0; i < 10; ++i) {
        v[i].x = __expf(v[i].x - m); v[i].y = __expf(v[i].y - m);
        v[i].z = __expf(v[i].z - m); v[i].w = __expf(v[i].w - m);
        sum += v[i].x + v[i].y + v[i].z + v[i].w;
    }
    float inv = 1.f / sum;
    float4* pr = reinterpret_cast<float4*>(PROBS + (size_t)n * GC);
#pragma unroll
    for (int i = 0; i < 10; ++i) {
        v[i].x *= inv; v[i].y *= inv; v[i].z *= inv; v[i].w *= inv;
        pr[i] = v[i];
    }
}

extern "C" void kernel_launch(void* const* d_in, const int* in_sizes, int n_in,
                              void* d_out, int out_size, void* d_ws, size_t ws_size,
                              hipStream_t stream) {
    const int*   row  = (const int*)d_in[0];
    const int*   col  = (const int*)d_in[1];
    const float* vals = (const float*)d_in[2];
    const float* x    = (const float*)d_in[3];
    const float* w1   = (const float*)d_in[4];
    const float* w2   = (const float*)d_in[5];
    const float* wc   = (const float*)d_in[6];
    const float* bc   = (const float*)d_in[7];

    float* out   = (float*)d_out;                 // [N, D]
    float* probs = out + (size_t)GN * GD;         // [N, C]

    char*  ws  = (char*)d_ws;
    int*   rp  = (int*)ws;                                        // (N+1) ints
    size_t off = (((size_t)(GN + 1) * 4) + 511) & ~(size_t)511;
    unsigned* buf = (unsigned*)(ws + off);        // bf16 [N,96] (48 uints/row); reused as f32 logits
    off += (size_t)GN * GD * 4;
    off = (off + 511) & ~(size_t)511;
    int2* ep   = (int2*)(ws + off);               // [E] packed edges
    off += (size_t)GE * 8;
    off = (off + 511) & ~(size_t)511;
    unsigned* Wb1 = (unsigned*)(ws + off);        // 4608 uints (18 KB) MFMA B-frags of w1
    unsigned* Wb2 = Wb1 + 4608;                   // same for w2

    prep_k<<<(GE + 255) / 256, 256, 0, stream>>>(row, col, vals, rp, ep);
    wpack_k<<<(2 * 4608 + 255) / 256, 256, 0, stream>>>(w1, w2, Wb1, Wb2);
    // t1 = bf16(x @ w1)  [MFMA, split-A]
    gemm_mfma_k<<<GN / 16, 64, 0, stream>>>(x, (const uint4*)Wb1, (unsigned short*)buf);
    // h1 = relu(A @ t1) -> d_out (f32)
    spmm_relu_k<<<(GN * 8 + 255) / 256, 256, 0, stream>>>(rp, ep, buf, out);
    // t2 = bf16(h1 @ w2)  [MFMA, split-A]
    gemm_mfma_k<<<GN / 16, 64, 0, stream>>>(out, (const uint4*)Wb2, (unsigned short*)buf);
    // out = l2norm(relu(A @ t2))
    spmm_relu_norm_k<<<(GN * 8 + 255) / 256, 256, 0, stream>>>(rp, ep, buf, out);
    // logits = out @ wc + bc -> buf (f32) ; probs = softmax(logits)
    cls_gemm_k<<<((GN / 4) * 10 + 255) / 256, 256, 0, stream>>>(out, wc, bc, (float*)buf);
    softmax_k<<<(GN + 255) / 256, 256, 0, stream>>>((float*)buf, probs);
}

// Round 7
// 108.259 us; speedup vs baseline: 4.0464x; 1.0463x over previous
//
#include <hip/hip_runtime.h>
#include <hip/hip_bf16.h>

#define GN 50000
#define GE 800000
#define GD 96
#define GC 40
#define L2EPS 1e-12f

typedef __attribute__((ext_vector_type(8))) short short8v;   // 8 bf16 = 4 VGPR
typedef __attribute__((ext_vector_type(4))) float f32x4;

__device__ __forceinline__ unsigned f2bf(float x) {           // RNE float->bf16 bits
    union { float f; unsigned u; } v; v.f = x;
    return (v.u + 0x7fffu + ((v.u >> 16) & 1u)) >> 16;
}
__device__ __forceinline__ float bflo(unsigned u) { return __uint_as_float(u << 16); }
__device__ __forceinline__ float bfhi(unsigned u) { return __uint_as_float(u & 0xffff0000u); }

// merged prep: ep[e]=(col,val) ; rp[i]=lower_bound(row,i) ; Wb1/Wb2 MFMA B-frag packs
__global__ void prep_k(const int* __restrict__ row, const int* __restrict__ col,
                       const float* __restrict__ vals, const float* __restrict__ w1,
                       const float* __restrict__ w2, int* __restrict__ rp,
                       int2* __restrict__ ep, unsigned* __restrict__ Wb1,
                       unsigned* __restrict__ Wb2) {
    int i = blockIdx.x * blockDim.x + threadIdx.x;
    if (i < GE) ep[i] = make_int2(col[i], __float_as_int(vals[i]));
    if (i <= GN) {
        int lo = 0, hi = GE;
        while (lo < hi) {
            int mid = (lo + hi) >> 1;
            if (row[mid] < i) lo = mid + 1; else hi = mid;
        }
        rp[i] = lo;
    }
    if (i < 2 * 4608) {
        const float* W = (i < 4608) ? w1 : w2;
        unsigned* Wb   = (i < 4608) ? Wb1 : Wb2;
        int j = (i < 4608) ? i : i - 4608;
        int r = j & 3;
        int lane = (j >> 2) & 63;
        int frag = j >> 8;                 // 0..17
        int nt = frag / 3, kt = frag - nt * 3;
        int c = nt * 16 + (lane & 15);
        int k = kt * 32 + (lane >> 4) * 8 + r * 2;
        Wb[j] = f2bf(W[k * GD + c]) | (f2bf(W[(k + 1) * GD + c]) << 16);
    }
}

// O_bf16[N,96] = A_f32[N,96] @ W ; MFMA 16x16x32 bf16 with split-A (hi+lo -> A exact).
__global__ __launch_bounds__(64) void gemm_mfma_k(const float* __restrict__ A,
                                                  const uint4* __restrict__ Wb,
                                                  unsigned short* __restrict__ O) {
    const int tile = blockIdx.x;            // 0..3124
    const int l  = threadIdx.x;             // 0..63
    const int m  = l & 15;
    const int kg = l >> 4;

    const float* arow = A + (size_t)(tile * 16 + m) * GD + kg * 8;
    short8v ah[3], al[3];
#pragma unroll
    for (int kt = 0; kt < 3; ++kt) {
        const float4* ap = reinterpret_cast<const float4*>(arow + kt * 32);
        float4 x0 = ap[0], x1 = ap[1];
        uint4 H, L;
        H.x = f2bf(x0.x) | (f2bf(x0.y) << 16);
        H.y = f2bf(x0.z) | (f2bf(x0.w) << 16);
        H.z = f2bf(x1.x) | (f2bf(x1.y) << 16);
        H.w = f2bf(x1.z) | (f2bf(x1.w) << 16);
        L.x = f2bf(x0.x - bflo(H.x)) | (f2bf(x0.y - bfhi(H.x)) << 16);
        L.y = f2bf(x0.z - bflo(H.y)) | (f2bf(x0.w - bfhi(H.y)) << 16);
        L.z = f2bf(x1.x - bflo(H.z)) | (f2bf(x1.y - bfhi(H.z)) << 16);
        L.w = f2bf(x1.z - bflo(H.w)) | (f2bf(x1.w - bfhi(H.w)) << 16);
        union { uint4 u; short8v s; } ch, cl;
        ch.u = H; cl.u = L;
        ah[kt] = ch.s; al[kt] = cl.s;
    }

#pragma unroll
    for (int nt = 0; nt < 6; ++nt) {
        f32x4 acc = {0.f, 0.f, 0.f, 0.f};
#pragma unroll
        for (int kt = 0; kt < 3; ++kt) {
            union { uint4 u; short8v s; } b;
            b.u = Wb[(nt * 3 + kt) * 64 + l];
            acc = __builtin_amdgcn_mfma_f32_16x16x32_bf16(ah[kt], b.s, acc, 0, 0, 0);
            acc = __builtin_amdgcn_mfma_f32_16x16x32_bf16(al[kt], b.s, acc, 0, 0, 0);
        }
        int ccol = nt * 16 + m;
#pragma unroll
        for (int reg = 0; reg < 4; ++reg) {
            int rrow = tile * 16 + kg * 4 + reg;
            O[(size_t)rrow * GD + ccol] = (unsigned short)f2bf(acc[reg]);
        }
    }
}

// 12 threads/node; lane t gathers exactly one uint4 (8 bf16 cols t*8..t*8+7) per edge.
__global__ void spmm_relu_k(const int* __restrict__ rp, const int2* __restrict__ ep,
                            const unsigned* __restrict__ Tb, float* __restrict__ H) {
    int idx = blockIdx.x * blockDim.x + threadIdx.x;
    int n = idx / 12;
    if (n >= GN) return;
    int t = idx - n * 12;
    int e0 = rp[n], e1 = rp[n + 1];
    float a0=0,a1=0,a2=0,a3=0,a4=0,a5=0,a6=0,a7=0;
#pragma unroll 2
    for (int e = e0; e < e1; ++e) {
        int2 p = ep[e];
        float v = __int_as_float(p.y);
        uint4 u = *reinterpret_cast<const uint4*>(Tb + (size_t)p.x * 48 + t * 4);
        a0 += v * bflo(u.x); a1 += v * bfhi(u.x);
        a2 += v * bflo(u.y); a3 += v * bfhi(u.y);
        a4 += v * bflo(u.z); a5 += v * bfhi(u.z);
        a6 += v * bflo(u.w); a7 += v * bfhi(u.w);
    }
    float4* hr = reinterpret_cast<float4*>(H + (size_t)n * GD + t * 8);
    hr[0] = make_float4(fmaxf(a0,0.f), fmaxf(a1,0.f), fmaxf(a2,0.f), fmaxf(a3,0.f));
    hr[1] = make_float4(fmaxf(a4,0.f), fmaxf(a5,0.f), fmaxf(a6,0.f), fmaxf(a7,0.f));
}

// fused: out = l2norm(relu(A @ t2)) ; probs = softmax(out @ wc + bc)
// block = 192 threads = 16 nodes x 12 lanes
__global__ __launch_bounds__(192) void spmm_norm_cls_k(
        const int* __restrict__ rp, const int2* __restrict__ ep,
        const unsigned* __restrict__ Tb, const float* __restrict__ WC,
        const float* __restrict__ BC, float* __restrict__ H,
        float* __restrict__ PROBS) {
    __shared__ float  wlds[GD * GC];       // 15360 B, [k][c]
    __shared__ float  sq[192];
    __shared__ float  srow[16][100];       // stride 100 breaks 96%32==0 banking
    __shared__ float  smax[16][10];
    __shared__ float  selse[16][GC];       // exp values

    const int tid = threadIdx.x;
    {
        float4* w4 = reinterpret_cast<float4*>(wlds);
        const float4* W4 = reinterpret_cast<const float4*>(WC);
        for (int i = tid; i < GD * GC / 4; i += 192) w4[i] = W4[i];
    }
    const int g = tid / 12;
    const int t = tid - g * 12;
    const int n = blockIdx.x * 16 + g;
    int e0 = rp[n], e1 = rp[n + 1];
    float a0=0,a1=0,a2=0,a3=0,a4=0,a5=0,a6=0,a7=0;
#pragma unroll 2
    for (int e = e0; e < e1; ++e) {
        int2 p = ep[e];
        float v = __int_as_float(p.y);
        uint4 u = *reinterpret_cast<const uint4*>(Tb + (size_t)p.x * 48 + t * 4);
        a0 += v * bflo(u.x); a1 += v * bfhi(u.x);
        a2 += v * bflo(u.y); a3 += v * bfhi(u.y);
        a4 += v * bflo(u.z); a5 += v * bfhi(u.z);
        a6 += v * bflo(u.w); a7 += v * bfhi(u.w);
    }
    a0=fmaxf(a0,0.f); a1=fmaxf(a1,0.f); a2=fmaxf(a2,0.f); a3=fmaxf(a3,0.f);
    a4=fmaxf(a4,0.f); a5=fmaxf(a5,0.f); a6=fmaxf(a6,0.f); a7=fmaxf(a7,0.f);
    sq[tid] = a0*a0+a1*a1+a2*a2+a3*a3+a4*a4+a5*a5+a6*a6+a7*a7;
    __syncthreads();
    float s2 = 0.f;
#pragma unroll
    for (int j = 0; j < 12; ++j) s2 += sq[g * 12 + j];
    float s = rsqrtf(fmaxf(s2, L2EPS));
    a0*=s; a1*=s; a2*=s; a3*=s; a4*=s; a5*=s; a6*=s; a7*=s;
    float4* hr = reinterpret_cast<float4*>(H + (size_t)n * GD + t * 8);
    hr[0] = make_float4(a0, a1, a2, a3);
    hr[1] = make_float4(a4, a5, a6, a7);
    float* sr = &srow[g][t * 8];
    sr[0]=a0; sr[1]=a1; sr[2]=a2; sr[3]=a3; sr[4]=a4; sr[5]=a5; sr[6]=a6; sr[7]=a7;
    __syncthreads();

    // classifier: lanes t<10 each compute 4 logits (c = t*4 .. t*4+3)
    float4 acc = {0.f, 0.f, 0.f, 0.f};
    if (t < 10) {
        const float4* wl4 = reinterpret_cast<const float4*>(wlds);
        const float* row = srow[g];
        acc = *reinterpret_cast<const float4*>(BC + t * 4);
#pragma unroll 8
        for (int k = 0; k < GD; ++k) {
            float sv = row[k];
            float4 w = wl4[k * 10 + t];
            acc.x += sv * w.x; acc.y += sv * w.y; acc.z += sv * w.z; acc.w += sv * w.w;
        }
        smax[g][t] = fmaxf(fmaxf(acc.x, acc.y), fmaxf(acc.z, acc.w));
    }
    __syncthreads();
    if (t < 10) {
        float m = smax[g][0];
#pragma unroll
        for (int j = 1; j < 10; ++j) m = fmaxf(m, smax[g][j]);
        acc.x = __expf(acc.x - m); acc.y = __expf(acc.y - m);
        acc.z = __expf(acc.z - m); acc.w = __expf(acc.w - m);
        *reinterpret_cast<float4*>(&selse[g][t * 4]) = acc;
    }
    __syncthreads();
    if (t < 10) {
        float sum = 0.f;
#pragma unroll
        for (int j = 0; j < GC; ++j) sum += selse[g][j];
        float inv = 1.f / sum;
        acc.x *= inv; acc.y *= inv; acc.z *= inv; acc.w *= inv;
        *reinterpret_cast<float4*>(PROBS + (size_t)n * GC + t * 4) = acc;
    }
}

extern "C" void kernel_launch(void* const* d_in, const int* in_sizes, int n_in,
                              void* d_out, int out_size, void* d_ws, size_t ws_size,
                              hipStream_t stream) {
    const int*   row  = (const int*)d_in[0];
    const int*   col  = (const int*)d_in[1];
    const float* vals = (const float*)d_in[2];
    const float* x    = (const float*)d_in[3];
    const float* w1   = (const float*)d_in[4];
    const float* w2   = (const float*)d_in[5];
    const float* wc   = (const float*)d_in[6];
    const float* bc   = (const float*)d_in[7];

    float* out   = (float*)d_out;                 // [N, D]
    float* probs = out + (size_t)GN * GD;         // [N, C]

    char*  ws  = (char*)d_ws;
    int*   rp  = (int*)ws;                                        // (N+1) ints
    size_t off = (((size_t)(GN + 1) * 4) + 511) & ~(size_t)511;
    unsigned* buf = (unsigned*)(ws + off);        // bf16 [N,96] (48 uints/row)
    off += (size_t)GN * GD * 4;
    off = (off + 511) & ~(size_t)511;
    int2* ep   = (int2*)(ws + off);               // [E] packed edges
    off += (size_t)GE * 8;
    off = (off + 511) & ~(size_t)511;
    unsigned* Wb1 = (unsigned*)(ws + off);        // 4608 uints MFMA B-frags of w1
    unsigned* Wb2 = Wb1 + 4608;

    // prep: edges + row ptrs + W packs
    prep_k<<<(GE + 255) / 256, 256, 0, stream>>>(row, col, vals, w1, w2, rp, ep, Wb1, Wb2);
    // t1 = bf16(x @ w1)
    gemm_mfma_k<<<GN / 16, 64, 0, stream>>>(x, (const uint4*)Wb1, (unsigned short*)buf);
    // h1 = relu(A @ t1) -> d_out (f32)
    spmm_relu_k<<<(GN * 12 + 255) / 256, 256, 0, stream>>>(rp, ep, buf, out);
    // t2 = bf16(h1 @ w2)
    gemm_mfma_k<<<GN / 16, 64, 0, stream>>>(out, (const uint4*)Wb2, (unsigned short*)buf);
    // out = l2norm(relu(A @ t2)) ; probs = softmax(out @ wc + bc)
    spmm_norm_cls_k<<<GN / 16, 192, 0, stream>>>(rp, ep, buf, wc, bc, out, probs);
}